// Round 5
// baseline (203.995 us; speedup 1.0000x reference)
//
#include <hip/hip_runtime.h>

#define DD   32
#define HH   256
#define BB   4096
#define RR   2      // rows per wave
#define EPSF 1e-12f

// ---------------------------------------------------------------------------
// Degree-sorted layout. deg_h[h] = (h%31)+1. Counts: deg 1..8 -> 9, 9..31 -> 8.
// Sorted position p -> original h:
//   p < 72:  h = (p/9) + 31*(p%9)
//   p >= 72: h = (8+(p-72)/8) + 31*((p-72)%8)
// Group deg==d occupies sorted positions [OFF(d), OFF(d+1)),
//   OFF(d) = (d<=9) ? 9*(d-1) : 8*d   (d>=1; OFF(1)=0, OFF(32)=256)
// ---------------------------------------------------------------------------
__device__ __forceinline__ int made_pi(int p) {
    return (p < 72) ? (p / 9) + 31 * (p % 9)
                    : (8 + (p - 72) / 8) + 31 * ((p - 72) % 8);
}
__device__ __forceinline__ int made_off(int d) {   // d >= 1
    return (d <= 9) ? 9 * (d - 1) : 8 * d;
}

// ws float layout:
//   per net n (n=0 mu, n=1 lv), base n*NETF:
//     W0s[32][256] @0 | W1s[256][256] @8192 | b0s[256] @73728 | b1s[256] @73984
//   shared W2i[256][2][32] @ 2*NETF   (W2i[p][n][dd] = Wn2[h(p)][dd])
#define NW0   (DD * HH)                 // 8192
#define NW1   (HH * HH)                 // 65536
#define NETF  (NW0 + NW1 + HH + HH)     // 74240
#define W2IOFF (2 * NETF)
#define NW2I  (HH * 64)                 // 16384
#define WSNEED ((size_t)(W2IOFF + NW2I) * 4)

// LDS weight-buffer layout (floats), double-buffered:
//   w1m rows0..8 @0 | w1l rows0..8 @2304 | w0m @4608 | w0l @4864 | w2 @5120
#define LW1L  2304
#define LW0M  4608
#define LW0L  4864
#define LW2   5120
#define LDSZ  5696
#define NSTG  1424   // total float4 chunks staged per step: 1152 w1 + 128 w0 + 144 w2

// ---------------------------------------------------------------------------
// Prep: blocks 0..511 -> W1 rows (LDS-staged permute) + biases;
//       blocks 512..767 -> W2i rows; blocks 768..831 -> W0 rows.
// ---------------------------------------------------------------------------
__global__ void made_prep(
    const float* __restrict__ muW0, const float* __restrict__ mub0,
    const float* __restrict__ muW1, const float* __restrict__ mub1,
    const float* __restrict__ muW2,
    const float* __restrict__ lvW0, const float* __restrict__ lvb0,
    const float* __restrict__ lvW1, const float* __restrict__ lvb1,
    const float* __restrict__ lvW2,
    float* __restrict__ ws)
{
    const int t = threadIdx.x;           // 0..63
    const int b = blockIdx.x;
    __shared__ float rowbuf[HH];

    if (b < 512) {
        const int n = b >> 8, p = b & 255;
        const int h = made_pi(p);
        const float* W1 = n ? lvW1 : muW1;
        float* o = ws + (size_t)n * NETF;
        *reinterpret_cast<float4*>(&rowbuf[4 * t]) =
            *reinterpret_cast<const float4*>(W1 + h * HH + 4 * t);
        __syncthreads();
        float4 w;
        w.x = rowbuf[made_pi(4 * t + 0)];
        w.y = rowbuf[made_pi(4 * t + 1)];
        w.z = rowbuf[made_pi(4 * t + 2)];
        w.w = rowbuf[made_pi(4 * t + 3)];
        *reinterpret_cast<float4*>(o + NW0 + p * HH + 4 * t) = w;
        if (t == 0) {
            o[NW0 + NW1 + p]      = (n ? lvb0 : mub0)[h];
            o[NW0 + NW1 + HH + p] = (n ? lvb1 : mub1)[h];
        }
    } else if (b < 768) {
        const int p = b - 512;           // sorted position
        const int h = made_pi(p);
        const int n = t >> 5, dd = t & 31;
        ws[W2IOFF + p * 64 + t] = (n ? lvW2 : muW2)[h * DD + dd];
    } else {
        const int idx = b - 768;         // 0..63
        const int n = idx >> 5, i = idx & 31;
        const float* W0 = n ? lvW0 : muW0;
        float* o = ws + (size_t)n * NETF;
        *reinterpret_cast<float4*>(&rowbuf[4 * t]) =
            *reinterpret_cast<const float4*>(W0 + i * HH + 4 * t);
        __syncthreads();
        float4 w;
        w.x = rowbuf[made_pi(4 * t + 0)];
        w.y = rowbuf[made_pi(4 * t + 1)];
        w.z = rowbuf[made_pi(4 * t + 2)];
        w.w = rowbuf[made_pi(4 * t + 3)];
        *reinterpret_cast<float4*>(o + i * HH + 4 * t) = w;
    }
}

// Stage-map: float4 chunk index i (0..NSTG) for step dn -> global src pointer.
__device__ __forceinline__ const float4* stage_src(
    int i, int dn,
    const float* __restrict__ W1m, const float* __restrict__ W1l,
    const float* __restrict__ W0m, const float* __restrict__ W0l,
    const float* __restrict__ W2i)
{
    const int offn = made_off(dn);
    if (i < 1152) {                       // W1: 2 nets x 9 rows x 64 float4
        const int net = i >= 576;
        const int ii  = net ? i - 576 : i;
        const int row9 = ii >> 6, c4i = ii & 63;
        int grow = offn + row9; if (grow > 255) grow = 255;   // r8 clamp (masked for d>=9)
        const float* W1 = net ? W1l : W1m;
        return reinterpret_cast<const float4*>(W1 + grow * HH + 4 * c4i);
    } else if (i < 1280) {                // W0 row dn-1: 2 nets x 64 float4
        const int j = i - 1152, net = j >> 6, c4i = j & 63;
        const float* W0 = net ? W0l : W0m;
        return reinterpret_cast<const float4*>(W0 + (dn - 1) * HH + 4 * c4i);
    } else {                              // W2: 9 rows x 16 float4
        const int j = i - 1280, row9 = j >> 4, c4i = j & 15;
        int grow = offn + row9; if (grow > 255) grow = 255;
        return reinterpret_cast<const float4*>(W2i + grow * 64 + 4 * c4i);
    }
}
__device__ __forceinline__ int stage_dst(int i) {  // float offset into WB buffer
    if (i < 1152) {
        const int net = i >= 576;
        const int ii  = net ? i - 576 : i;
        return net * LW1L + (ii >> 6) * 256 + 4 * (ii & 63);
    } else if (i < 1280) {
        const int j = i - 1152;
        return LW0M + (j >> 6) * 256 + 4 * (j & 63);
    } else {
        const int j = i - 1280;
        return LW2 + (j >> 4) * 64 + 4 * (j & 15);
    }
}

// ---------------------------------------------------------------------------
// Main: R11 = R7 compute structure (verified 66 us) + block-level LDS weight
// staging. R9/R10 falsified the TLP theory (more waves = worse); all rounds
// fit an L1-return-BW bound: each wave re-read 22.3 KB/step (8 waves/CU x
// 31 steps ~= 44 us of L1 service). Now ONE cooperative staging per block
// per step (double-buffered WB, 1 barrier/step) serves all 4 waves from LDS:
// global traffic /4, weight reads move to the LDS pipe which overlaps VALU.
// T14 split: stage loads issued at step top, ds_writes after compute.
// ---------------------------------------------------------------------------
__global__ __launch_bounds__(256, 2) void made_main(
    const float* __restrict__ ws, const float* __restrict__ x,
    const float* __restrict__ mub2, const float* __restrict__ lvb2,
    float* __restrict__ out)
{
    const int t    = threadIdx.x;
    const int lane = t & 63;
    const int wv   = t >> 6;
    const int row0 = ((blockIdx.x << 2) + wv) * RR;
    const int c4   = lane << 2;          // base sorted position (4 slots/lane)
    const int nn   = lane >> 5;          // net of this lane's output acc
    const int ddl  = lane & 31;          // output dim of this lane's acc

    const float* W1m = ws + NW0;
    const float* W1l = ws + NETF + NW0;
    const float* W0m = ws;
    const float* W0l = ws + NETF;
    const float* W2i = ws + W2IOFF;

    __shared__ float WB[2][LDSZ];       // double-buffered step weights
    __shared__ float A[4][2][RR][12];   // relu(h0) of finalizing group (wave-private)
    __shared__ float Bf[4][2][RR][12];  // relu(h1) of finalizing group (wave-private)

    float h0[2][4][RR], h1[2][4][RR];
    #pragma unroll
    for (int n = 0; n < 2; ++n) {
        const float* bb = ws + (size_t)n * NETF + NW0 + NW1;
        const float4 v0 = *reinterpret_cast<const float4*>(bb + c4);
        const float4 v1 = *reinterpret_cast<const float4*>(bb + HH + c4);
        const float a0[4] = {v0.x, v0.y, v0.z, v0.w};
        const float a1[4] = {v1.x, v1.y, v1.z, v1.w};
        #pragma unroll
        for (int s = 0; s < 4; ++s)
            #pragma unroll
            for (int r = 0; r < RR; ++r) { h0[n][s][r] = a0[s]; h1[n][s][r] = a1[s]; }
    }

    // output accumulators (start at b2 of this lane's (net, dim))
    const float accinit = nn ? lvb2[ddl] : mub2[ddl];
    float acc[RR];
    #pragma unroll
    for (int r = 0; r < RR; ++r) acc[r] = accinit;

    // x preload for broadcast: lane l holds x[row_r][l&31]
    float xvr[RR];
    #pragma unroll
    for (int r = 0; r < RR; ++r) xvr[r] = x[(row0 + r) * DD + ddl];

    float yprev[RR], lsum[RR], ysave[RR];
    #pragma unroll
    for (int r = 0; r < RR; ++r) { lsum[r] = 0.f; ysave[r] = 0.f; }

    // ---- prologue: issue stage loads for step 1 into WB[1]
    float4 st[6];
    #pragma unroll
    for (int it = 0; it < 6; ++it) {
        const int i = t + it * 256;
        if (i < NSTG) st[it] = *stage_src(i, 1, W1m, W1l, W0m, W0l, W2i);
    }

    // ---- step d = 0: no hidden unit finalized yet; acc == b2
    #pragma unroll
    for (int r = 0; r < RR; ++r) {
        const float mu  = __shfl(acc[r], 0, 64);
        const float lv  = __shfl(acc[r], 32, 64);
        const float ls2 = 0.5f * lv;
        lsum[r] += ls2;
        const float yd = (__shfl(xvr[r], 0, 64) - mu) / (__expf(ls2) + EPSF);
        yprev[r] = yd;
        if (lane == 0) ysave[r] = yd;
    }

    // ---- prologue: commit stage for step 1
    #pragma unroll
    for (int it = 0; it < 6; ++it) {
        const int i = t + it * 256;
        if (i < NSTG) *reinterpret_cast<float4*>(&WB[1][stage_dst(i)]) = st[it];
    }
    __syncthreads();

    for (int d = 1; d < DD; ++d) {
        const int off = made_off(d);
        const int nk  = (d <= 8) ? 9 : 8;           // group size
        const float* wb = &WB[d & 1][0];
        const int nst = (d < DD - 1) ? NSTG : 0;    // no stage after last step

        // ============ issue next-step stage loads (overlap with compute) ===
        #pragma unroll
        for (int it = 0; it < 6; ++it) {
            const int i = t + it * 256;
            if (i < nst) st[it] = *stage_src(i, d + 1, W1m, W1l, W0m, W0l, W2i);
        }

        // ============ read this step's weights from LDS ====================
        const float4 w0m = *reinterpret_cast<const float4*>(wb + LW0M + c4);
        const float4 w0l = *reinterpret_cast<const float4*>(wb + LW0L + c4);
        float4 w1m[9], w1l[9];
        #pragma unroll
        for (int k = 0; k < 9; ++k) {
            w1m[k] = *reinterpret_cast<const float4*>(wb + k * HH + c4);
            w1l[k] = *reinterpret_cast<const float4*>(wb + LW1L + k * HH + c4);
        }
        float w2[9];
        #pragma unroll
        for (int k = 0; k < 9; ++k) w2[k] = wb[LW2 + k * 64 + lane];

        // ================= h0 += y_{d-1} * W0s[d-1,:] (all lanes) ==========
        #pragma unroll
        for (int r = 0; r < RR; ++r) {
            h0[0][0][r] = fmaf(yprev[r], w0m.x, h0[0][0][r]);
            h0[0][1][r] = fmaf(yprev[r], w0m.y, h0[0][1][r]);
            h0[0][2][r] = fmaf(yprev[r], w0m.z, h0[0][2][r]);
            h0[0][3][r] = fmaf(yprev[r], w0m.w, h0[0][3][r]);
            h0[1][0][r] = fmaf(yprev[r], w0l.x, h0[1][0][r]);
            h0[1][1][r] = fmaf(yprev[r], w0l.y, h0[1][1][r]);
            h0[1][2][r] = fmaf(yprev[r], w0l.z, h0[1][2][r]);
            h0[1][3][r] = fmaf(yprev[r], w0l.w, h0[1][3][r]);
        }

        // zero the k=8 broadcast slots when the group has only 8 members
        if (d >= 9 && lane == 0) {
            #pragma unroll
            for (int n = 0; n < 2; ++n)
                #pragma unroll
                for (int r = 0; r < RR; ++r) {
                    A[wv][n][r][8]  = 0.f;
                    Bf[wv][n][r][8] = 0.f;
                }
        }
        // finalize relu(h0) -> A (ONLY the nk members of group d)
        #pragma unroll
        for (int s = 0; s < 4; ++s) {
            const int k = c4 + s - off;
            if ((unsigned)k < (unsigned)nk) {
                #pragma unroll
                for (int r = 0; r < RR; ++r) {
                    A[wv][0][r][k] = fmaxf(h0[0][s][r], 0.f);
                    A[wv][1][r][k] = fmaxf(h0[1][s][r], 0.f);
                }
            }
        }
        // read broadcast av (wave-private LDS; program order guarantees vis.)
        float av[2][RR][9];
        #pragma unroll
        for (int n = 0; n < 2; ++n)
            #pragma unroll
            for (int r = 0; r < RR; ++r) {
                const float4 a03 = *reinterpret_cast<const float4*>(&A[wv][n][r][0]);
                const float4 a47 = *reinterpret_cast<const float4*>(&A[wv][n][r][4]);
                av[n][r][0] = a03.x; av[n][r][1] = a03.y;
                av[n][r][2] = a03.z; av[n][r][3] = a03.w;
                av[n][r][4] = a47.x; av[n][r][5] = a47.y;
                av[n][r][6] = a47.z; av[n][r][7] = a47.w;
                av[n][r][8] = A[wv][n][r][8];
            }

        // ================= h1 += av[k] * W1s[row k] — uniform 9 ============
        #pragma unroll
        for (int k = 0; k < 9; ++k) {
            #pragma unroll
            for (int r = 0; r < RR; ++r) {
                h1[0][0][r] = fmaf(av[0][r][k], w1m[k].x, h1[0][0][r]);
                h1[0][1][r] = fmaf(av[0][r][k], w1m[k].y, h1[0][1][r]);
                h1[0][2][r] = fmaf(av[0][r][k], w1m[k].z, h1[0][2][r]);
                h1[0][3][r] = fmaf(av[0][r][k], w1m[k].w, h1[0][3][r]);
                h1[1][0][r] = fmaf(av[1][r][k], w1l[k].x, h1[1][0][r]);
                h1[1][1][r] = fmaf(av[1][r][k], w1l[k].y, h1[1][1][r]);
                h1[1][2][r] = fmaf(av[1][r][k], w1l[k].z, h1[1][2][r]);
                h1[1][3][r] = fmaf(av[1][r][k], w1l[k].w, h1[1][3][r]);
            }
        }

        // finalize relu(h1) -> Bf (ONLY the nk members of group d)
        #pragma unroll
        for (int s = 0; s < 4; ++s) {
            const int k = c4 + s - off;
            if ((unsigned)k < (unsigned)nk) {
                #pragma unroll
                for (int r = 0; r < RR; ++r) {
                    Bf[wv][0][r][k] = fmaxf(h1[0][s][r], 0.f);
                    Bf[wv][1][r][k] = fmaxf(h1[1][s][r], 0.f);
                }
            }
        }
        // read r1 broadcast for this lane's net, fold into output accs
        float rb[RR][9];
        #pragma unroll
        for (int r = 0; r < RR; ++r) {
            const float4 b03 = *reinterpret_cast<const float4*>(&Bf[wv][nn][r][0]);
            const float4 b47 = *reinterpret_cast<const float4*>(&Bf[wv][nn][r][4]);
            rb[r][0] = b03.x; rb[r][1] = b03.y; rb[r][2] = b03.z; rb[r][3] = b03.w;
            rb[r][4] = b47.x; rb[r][5] = b47.y; rb[r][6] = b47.z; rb[r][7] = b47.w;
            rb[r][8] = Bf[wv][nn][r][8];
        }
        #pragma unroll
        for (int k = 0; k < 9; ++k)
            #pragma unroll
            for (int r = 0; r < RR; ++r)
                acc[r] = fmaf(rb[r][k], w2[k], acc[r]);

        // ================= outputs for dim d ===============================
        #pragma unroll
        for (int r = 0; r < RR; ++r) {
            const float mu  = __shfl(acc[r], d, 64);
            const float lv  = __shfl(acc[r], 32 + d, 64);
            const float ls2 = 0.5f * lv;
            lsum[r] += ls2;
            const float yd = (__shfl(xvr[r], d, 64) - mu) / (__expf(ls2) + EPSF);
            yprev[r] = yd;
            if (lane == d) ysave[r] = yd;
        }

        // ============ commit next-step stage, buffer handoff ===============
        #pragma unroll
        for (int it = 0; it < 6; ++it) {
            const int i = t + it * 256;
            if (i < nst) *reinterpret_cast<float4*>(&WB[(d + 1) & 1][stage_dst(i)]) = st[it];
        }
        __syncthreads();
    }

    #pragma unroll
    for (int r = 0; r < RR; ++r) {
        if (lane < DD) out[(row0 + r) * DD + lane] = ysave[r];   // coalesced
        if (lane == 0) out[BB * DD + row0 + r] = lsum[r];
    }
}

// ---------------------------------------------------------------------------
// Fallback (no workspace): R1-style kernel.
// ---------------------------------------------------------------------------
__global__ __launch_bounds__(64, 1) void made_inv_fb(
    const float* __restrict__ x,
    const float* __restrict__ muW0, const float* __restrict__ mub0,
    const float* __restrict__ muW1, const float* __restrict__ mub1,
    const float* __restrict__ muW2, const float* __restrict__ mub2,
    const float* __restrict__ lvW0, const float* __restrict__ lvb0,
    const float* __restrict__ lvW1, const float* __restrict__ lvb1,
    const float* __restrict__ lvW2, const float* __restrict__ lvb2,
    float* __restrict__ out)
{
    const int lane    = threadIdx.x;
    const int rowBase = blockIdx.x * 4;
    const int hb      = lane << 2;
    int deg[4];
    #pragma unroll
    for (int s = 0; s < 4; ++s) deg[s] = ((hb + s) % 31) + 1;
    const float* Wp0[2] = {muW0, lvW0};
    const float* Bp0[2] = {mub0, lvb0};
    const float* Wp1[2] = {muW1, lvW1};
    const float* Bp1[2] = {mub1, lvb1};
    const float* Wp2[2] = {muW2, lvW2};
    float h0pre[2][4][4], h1pre[2][4][4], r1[2][4][4], yprev[4], lsum[4];
    #pragma unroll
    for (int n = 0; n < 2; ++n) {
        const float4 b0v = *reinterpret_cast<const float4*>(Bp0[n] + hb);
        const float4 b1v = *reinterpret_cast<const float4*>(Bp1[n] + hb);
        const float b0a[4] = {b0v.x, b0v.y, b0v.z, b0v.w};
        const float b1a[4] = {b1v.x, b1v.y, b1v.z, b1v.w};
        #pragma unroll
        for (int s = 0; s < 4; ++s)
            #pragma unroll
            for (int r = 0; r < 4; ++r) {
                h0pre[n][s][r] = b0a[s]; h1pre[n][s][r] = b1a[s]; r1[n][s][r] = 0.f;
            }
    }
    #pragma unroll
    for (int r = 0; r < 4; ++r) { yprev[r] = 0.f; lsum[r] = 0.f; }
    __shared__ float lds_a[2][4][12];
    for (int d = 0; d < DD; ++d) {
        if (d >= 1) {
            #pragma unroll
            for (int n = 0; n < 2; ++n) {
                const float4 w0 = *reinterpret_cast<const float4*>(Wp0[n] + (d - 1) * HH + hb);
                const float w0a[4] = {w0.x, w0.y, w0.z, w0.w};
                #pragma unroll
                for (int s = 0; s < 4; ++s)
                    #pragma unroll
                    for (int r = 0; r < 4; ++r)
                        h0pre[n][s][r] = fmaf(yprev[r], w0a[s], h0pre[n][s][r]);
            }
            #pragma unroll
            for (int n = 0; n < 2; ++n)
                #pragma unroll
                for (int s = 0; s < 4; ++s)
                    if (deg[s] == d) {
                        const int k = (hb + s - (d - 1)) / 31;
                        #pragma unroll
                        for (int r = 0; r < 4; ++r)
                            lds_a[n][r][k] = fmaxf(h0pre[n][s][r], 0.f);
                    }
            __syncthreads();
            const bool nine = (d <= 8);
            #pragma unroll
            for (int n = 0; n < 2; ++n) {
                const float* W1r = Wp1[n] + (size_t)(d - 1) * HH + hb;
                float4 w1v[9];
                #pragma unroll
                for (int k = 0; k < 8; ++k)
                    w1v[k] = *reinterpret_cast<const float4*>(W1r + k * 31 * HH);
                if (nine) w1v[8] = *reinterpret_cast<const float4*>(W1r + 8 * 31 * HH);
                #pragma unroll
                for (int r = 0; r < 4; ++r) {
                    const float4 a03 = *reinterpret_cast<const float4*>(&lds_a[n][r][0]);
                    const float4 a47 = *reinterpret_cast<const float4*>(&lds_a[n][r][4]);
                    const float av[8] = {a03.x, a03.y, a03.z, a03.w, a47.x, a47.y, a47.z, a47.w};
                    #pragma unroll
                    for (int k = 0; k < 8; ++k) {
                        const float wk[4] = {w1v[k].x, w1v[k].y, w1v[k].z, w1v[k].w};
                        #pragma unroll
                        for (int s = 0; s < 4; ++s)
                            h1pre[n][s][r] = fmaf(av[k], wk[s], h1pre[n][s][r]);
                    }
                    if (nine) {
                        const float a8 = lds_a[n][r][8];
                        const float wk[4] = {w1v[8].x, w1v[8].y, w1v[8].z, w1v[8].w};
                        #pragma unroll
                        for (int s = 0; s < 4; ++s)
                            h1pre[n][s][r] = fmaf(a8, wk[s], h1pre[n][s][r]);
                    }
                }
            }
            #pragma unroll
            for (int n = 0; n < 2; ++n)
                #pragma unroll
                for (int s = 0; s < 4; ++s)
                    if (deg[s] == d)
                        #pragma unroll
                        for (int r = 0; r < 4; ++r)
                            r1[n][s][r] = fmaxf(h1pre[n][s][r], 0.f);
            __syncthreads();
        }
        float w2v[2][4];
        #pragma unroll
        for (int n = 0; n < 2; ++n)
            #pragma unroll
            for (int s = 0; s < 4; ++s)
                w2v[n][s] = Wp2[n][(hb + s) * DD + d];
        float red[2][4];
        #pragma unroll
        for (int n = 0; n < 2; ++n)
            #pragma unroll
            for (int r = 0; r < 4; ++r) {
                float p = 0.f;
                #pragma unroll
                for (int s = 0; s < 4; ++s) p = fmaf(r1[n][s][r], w2v[n][s], p);
                red[n][r] = p;
            }
        #pragma unroll
        for (int m = 1; m < 64; m <<= 1)
            #pragma unroll
            for (int n = 0; n < 2; ++n)
                #pragma unroll
                for (int r = 0; r < 4; ++r)
                    red[n][r] += __shfl_xor(red[n][r], m, 64);
        const float b2m = mub2[d], b2l = lvb2[d];
        #pragma unroll
        for (int r = 0; r < 4; ++r) {
            const float mu = red[0][r] + b2m;
            const float logstd = 0.5f * (red[1][r] + b2l);
            lsum[r] += logstd;
            const float yd = (x[(rowBase + r) * DD + d] - mu) / (__expf(logstd) + EPSF);
            yprev[r] = yd;
            if (lane == 0) out[(rowBase + r) * DD + d] = yd;
        }
    }
    if (lane == 0)
        #pragma unroll
        for (int r = 0; r < 4; ++r) out[BB * DD + rowBase + r] = lsum[r];
}

extern "C" void kernel_launch(void* const* d_in, const int* in_sizes, int n_in,
                              void* d_out, int out_size, void* d_ws, size_t ws_size,
                              hipStream_t stream) {
    const float* x    = (const float*)d_in[0];
    const float* muW0 = (const float*)d_in[1];
    const float* mub0 = (const float*)d_in[2];
    const float* muW1 = (const float*)d_in[3];
    const float* mub1 = (const float*)d_in[4];
    const float* muW2 = (const float*)d_in[5];
    const float* mub2 = (const float*)d_in[6];
    const float* lvW0 = (const float*)d_in[7];
    const float* lvb0 = (const float*)d_in[8];
    const float* lvW1 = (const float*)d_in[9];
    const float* lvb1 = (const float*)d_in[10];
    const float* lvW2 = (const float*)d_in[11];
    const float* lvb2 = (const float*)d_in[12];
    float* out = (float*)d_out;

    if (ws_size >= WSNEED) {
        float* ws = (float*)d_ws;
        made_prep<<<dim3(832), dim3(64), 0, stream>>>(
            muW0, mub0, muW1, mub1, muW2,
            lvW0, lvb0, lvW1, lvb1, lvW2, ws);
        made_main<<<dim3(BB / (4 * RR)), dim3(256), 0, stream>>>(ws, x, mub2, lvb2, out);
    } else {
        made_inv_fb<<<dim3(BB / 4), dim3(64), 0, stream>>>(x,
            muW0, mub0, muW1, mub1, muW2, mub2,
            lvW0, lvb0, lvW1, lvb1, lvW2, lvb2, out);
    }
}

// Round 9
// 171.211 us; speedup vs baseline: 1.1915x; 1.1915x over previous
//
#include <hip/hip_runtime.h>

#define DD   32
#define HH   256
#define BB   4096
#define RR   2      // rows per wave
#define EPSF 1e-12f

// ---------------------------------------------------------------------------
// Degree-sorted layout. deg_h[h] = (h%31)+1. Counts: deg 1..8 -> 9, 9..31 -> 8.
// Sorted position p -> original h:
//   p < 72:  h = (p/9) + 31*(p%9)
//   p >= 72: h = (8+(p-72)/8) + 31*((p-72)%8)
// Group deg==d occupies sorted positions [OFF(d), OFF(d+1)),
//   OFF(d) = (d<=9) ? 9*(d-1) : 8*d   (d>=1; OFF(1)=0, OFF(32)=256)
// ---------------------------------------------------------------------------
__device__ __forceinline__ int made_pi(int p) {
    return (p < 72) ? (p / 9) + 31 * (p % 9)
                    : (8 + (p - 72) / 8) + 31 * ((p - 72) % 8);
}
__device__ __forceinline__ int made_off(int d) {   // d >= 1
    return (d <= 9) ? 9 * (d - 1) : 8 * d;
}

// ws float layout:
//   per net n (n=0 mu, n=1 lv), base n*NETF:
//     W0s[32][256] @0 | W1s[256][256] @8192 | b0s[256] @73728 | b1s[256] @73984
//   shared W2i[256][2][32] @ 2*NETF   (W2i[p][n][dd] = Wn2[h(p)][dd])
#define NW0   (DD * HH)                 // 8192
#define NW1   (HH * HH)                 // 65536
#define NETF  (NW0 + NW1 + HH + HH)     // 74240
#define W2IOFF (2 * NETF)
#define NW2I  (HH * 64)                 // 16384
#define WSNEED ((size_t)(W2IOFF + NW2I) * 4)

// LDS weight-buffer layout (floats), double-buffered:
//   w1m rows0..8 @0 | w1l rows0..8 @2304 | w0m @4608 | w0l @4864 | w2 @5120
#define LW1L  2304
#define LW0M  4608
#define LW0L  4864
#define LW2   5120
#define LDSZ  5696
#define NSTG  1424   // total float4 chunks staged per step: 1152 w1 + 128 w0 + 144 w2

// ---------------------------------------------------------------------------
// Prep: blocks 0..511 -> W1 rows (LDS-staged permute) + biases;
//       blocks 512..767 -> W2i rows; blocks 768..831 -> W0 rows.
// ---------------------------------------------------------------------------
__global__ void made_prep(
    const float* __restrict__ muW0, const float* __restrict__ mub0,
    const float* __restrict__ muW1, const float* __restrict__ mub1,
    const float* __restrict__ muW2,
    const float* __restrict__ lvW0, const float* __restrict__ lvb0,
    const float* __restrict__ lvW1, const float* __restrict__ lvb1,
    const float* __restrict__ lvW2,
    float* __restrict__ ws)
{
    const int t = threadIdx.x;           // 0..63
    const int b = blockIdx.x;
    __shared__ float rowbuf[HH];

    if (b < 512) {
        const int n = b >> 8, p = b & 255;
        const int h = made_pi(p);
        const float* W1 = n ? lvW1 : muW1;
        float* o = ws + (size_t)n * NETF;
        *reinterpret_cast<float4*>(&rowbuf[4 * t]) =
            *reinterpret_cast<const float4*>(W1 + h * HH + 4 * t);
        __syncthreads();
        float4 w;
        w.x = rowbuf[made_pi(4 * t + 0)];
        w.y = rowbuf[made_pi(4 * t + 1)];
        w.z = rowbuf[made_pi(4 * t + 2)];
        w.w = rowbuf[made_pi(4 * t + 3)];
        *reinterpret_cast<float4*>(o + NW0 + p * HH + 4 * t) = w;
        if (t == 0) {
            o[NW0 + NW1 + p]      = (n ? lvb0 : mub0)[h];
            o[NW0 + NW1 + HH + p] = (n ? lvb1 : mub1)[h];
        }
    } else if (b < 768) {
        const int p = b - 512;           // sorted position
        const int h = made_pi(p);
        const int n = t >> 5, dd = t & 31;
        ws[W2IOFF + p * 64 + t] = (n ? lvW2 : muW2)[h * DD + dd];
    } else {
        const int idx = b - 768;         // 0..63
        const int n = idx >> 5, i = idx & 31;
        const float* W0 = n ? lvW0 : muW0;
        float* o = ws + (size_t)n * NETF;
        *reinterpret_cast<float4*>(&rowbuf[4 * t]) =
            *reinterpret_cast<const float4*>(W0 + i * HH + 4 * t);
        __syncthreads();
        float4 w;
        w.x = rowbuf[made_pi(4 * t + 0)];
        w.y = rowbuf[made_pi(4 * t + 1)];
        w.z = rowbuf[made_pi(4 * t + 2)];
        w.w = rowbuf[made_pi(4 * t + 3)];
        *reinterpret_cast<float4*>(o + i * HH + 4 * t) = w;
    }
}

// Stage-map: float4 chunk index i (0..NSTG) for step dn -> global src pointer.
__device__ __forceinline__ const float4* stage_src(
    int i, int dn,
    const float* __restrict__ W1m, const float* __restrict__ W1l,
    const float* __restrict__ W0m, const float* __restrict__ W0l,
    const float* __restrict__ W2i)
{
    const int offn = made_off(dn);
    if (i < 1152) {                       // W1: 2 nets x 9 rows x 64 float4
        const int net = i >= 576;
        const int ii  = net ? i - 576 : i;
        const int row9 = ii >> 6, c4i = ii & 63;
        int grow = offn + row9; if (grow > 255) grow = 255;   // r8 clamp (masked for d>=9)
        const float* W1 = net ? W1l : W1m;
        return reinterpret_cast<const float4*>(W1 + grow * HH + 4 * c4i);
    } else if (i < 1280) {                // W0 row dn-1: 2 nets x 64 float4
        const int j = i - 1152, net = j >> 6, c4i = j & 63;
        const float* W0 = net ? W0l : W0m;
        return reinterpret_cast<const float4*>(W0 + (dn - 1) * HH + 4 * c4i);
    } else {                              // W2: 9 rows x 16 float4
        const int j = i - 1280, row9 = j >> 4, c4i = j & 15;
        int grow = offn + row9; if (grow > 255) grow = 255;
        return reinterpret_cast<const float4*>(W2i + grow * 64 + 4 * c4i);
    }
}
__device__ __forceinline__ int stage_dst(int i) {  // float offset into WB buffer
    if (i < 1152) {
        const int net = i >= 576;
        const int ii  = net ? i - 576 : i;
        return net * LW1L + (ii >> 6) * 256 + 4 * (ii & 63);
    } else if (i < 1280) {
        const int j = i - 1152;
        return LW0M + (j >> 6) * 256 + 4 * (j & 63);
    } else {
        const int j = i - 1280;
        return LW2 + (j >> 4) * 64 + 4 * (j & 15);
    }
}

// ---------------------------------------------------------------------------
// Main: R12 = R7 compute structure + block-level LDS weight staging with
// REGISTER-SAFE commit. R11 failed on implementation, not concept: holding
// st[6] across the compute phase spilled (WRITE_SIZE 544KB->13.7MB scratch,
// VALUBusy 25%). Now: (a) stage = load->ds_write immediately at step top
// (transient ~24 VGPRs, nothing held across compute); (b) weights read from
// WB LAZILY inside their consuming loops — LDS latency (~64cy) needs no
// burst prefetch, unlike the L1 path that forced R7's 90-VGPR burst.
// One barrier/step, double-buffered WB. Numerics identical to R7/R11.
// ---------------------------------------------------------------------------
__global__ __launch_bounds__(256, 2) void made_main(
    const float* __restrict__ ws, const float* __restrict__ x,
    const float* __restrict__ mub2, const float* __restrict__ lvb2,
    float* __restrict__ out)
{
    const int t    = threadIdx.x;
    const int lane = t & 63;
    const int wv   = t >> 6;
    const int row0 = ((blockIdx.x << 2) + wv) * RR;
    const int c4   = lane << 2;          // base sorted position (4 slots/lane)
    const int nn   = lane >> 5;          // net of this lane's output acc
    const int ddl  = lane & 31;          // output dim of this lane's acc

    const float* W1m = ws + NW0;
    const float* W1l = ws + NETF + NW0;
    const float* W0m = ws;
    const float* W0l = ws + NETF;
    const float* W2i = ws + W2IOFF;

    __shared__ float WB[2][LDSZ];       // double-buffered step weights
    __shared__ float A[4][2][RR][12];   // relu(h0) of finalizing group (wave-private)
    __shared__ float Bf[4][2][RR][12];  // relu(h1) of finalizing group (wave-private)

    float h0[2][4][RR], h1[2][4][RR];
    #pragma unroll
    for (int n = 0; n < 2; ++n) {
        const float* bb = ws + (size_t)n * NETF + NW0 + NW1;
        const float4 v0 = *reinterpret_cast<const float4*>(bb + c4);
        const float4 v1 = *reinterpret_cast<const float4*>(bb + HH + c4);
        const float a0[4] = {v0.x, v0.y, v0.z, v0.w};
        const float a1[4] = {v1.x, v1.y, v1.z, v1.w};
        #pragma unroll
        for (int s = 0; s < 4; ++s)
            #pragma unroll
            for (int r = 0; r < RR; ++r) { h0[n][s][r] = a0[s]; h1[n][s][r] = a1[s]; }
    }

    // output accumulators (start at b2 of this lane's (net, dim))
    const float accinit = nn ? lvb2[ddl] : mub2[ddl];
    float acc[RR];
    #pragma unroll
    for (int r = 0; r < RR; ++r) acc[r] = accinit;

    // x preload for broadcast: lane l holds x[row_r][l&31]
    float xvr[RR];
    #pragma unroll
    for (int r = 0; r < RR; ++r) xvr[r] = x[(row0 + r) * DD + ddl];

    float yprev[RR], lsum[RR], ysave[RR];
    #pragma unroll
    for (int r = 0; r < RR; ++r) { lsum[r] = 0.f; ysave[r] = 0.f; }

    // ---- prologue: stage step 1 into WB[1] (immediate load->write)
    #pragma unroll
    for (int it = 0; it < 6; ++it) {
        const int i = t + it * 256;
        if (i < NSTG)
            *reinterpret_cast<float4*>(&WB[1][stage_dst(i)]) =
                *stage_src(i, 1, W1m, W1l, W0m, W0l, W2i);
    }

    // ---- step d = 0: no hidden unit finalized yet; acc == b2
    #pragma unroll
    for (int r = 0; r < RR; ++r) {
        const float mu  = __shfl(acc[r], 0, 64);
        const float lv  = __shfl(acc[r], 32, 64);
        const float ls2 = 0.5f * lv;
        lsum[r] += ls2;
        const float yd = (__shfl(xvr[r], 0, 64) - mu) / (__expf(ls2) + EPSF);
        yprev[r] = yd;
        if (lane == 0) ysave[r] = yd;
    }
    __syncthreads();

    for (int d = 1; d < DD; ++d) {
        const int off = made_off(d);
        const int nk  = (d <= 8) ? 9 : 8;           // group size
        const float* wb = &WB[d & 1][0];
        float* wbn      = &WB[(d + 1) & 1][0];
        const int nst = (d < DD - 1) ? NSTG : 0;    // no stage after last step

        // ============ stage next step's weights (immediate commit) =========
        #pragma unroll
        for (int it = 0; it < 6; ++it) {
            const int i = t + it * 256;
            if (i < nst)
                *reinterpret_cast<float4*>(&wbn[stage_dst(i)]) =
                    *stage_src(i, d + 1, W1m, W1l, W0m, W0l, W2i);
        }

        // ================= h0 += y_{d-1} * W0s[d-1,:] (all lanes) ==========
        {
            const float4 w0m = *reinterpret_cast<const float4*>(wb + LW0M + c4);
            const float4 w0l = *reinterpret_cast<const float4*>(wb + LW0L + c4);
            #pragma unroll
            for (int r = 0; r < RR; ++r) {
                h0[0][0][r] = fmaf(yprev[r], w0m.x, h0[0][0][r]);
                h0[0][1][r] = fmaf(yprev[r], w0m.y, h0[0][1][r]);
                h0[0][2][r] = fmaf(yprev[r], w0m.z, h0[0][2][r]);
                h0[0][3][r] = fmaf(yprev[r], w0m.w, h0[0][3][r]);
                h0[1][0][r] = fmaf(yprev[r], w0l.x, h0[1][0][r]);
                h0[1][1][r] = fmaf(yprev[r], w0l.y, h0[1][1][r]);
                h0[1][2][r] = fmaf(yprev[r], w0l.z, h0[1][2][r]);
                h0[1][3][r] = fmaf(yprev[r], w0l.w, h0[1][3][r]);
            }
        }

        // zero the k=8 broadcast slots when the group has only 8 members
        if (d >= 9 && lane == 0) {
            #pragma unroll
            for (int n = 0; n < 2; ++n)
                #pragma unroll
                for (int r = 0; r < RR; ++r) {
                    A[wv][n][r][8]  = 0.f;
                    Bf[wv][n][r][8] = 0.f;
                }
        }
        // finalize relu(h0) -> A (ONLY the nk members of group d)
        #pragma unroll
        for (int s = 0; s < 4; ++s) {
            const int k = c4 + s - off;
            if ((unsigned)k < (unsigned)nk) {
                #pragma unroll
                for (int r = 0; r < RR; ++r) {
                    A[wv][0][r][k] = fmaxf(h0[0][s][r], 0.f);
                    A[wv][1][r][k] = fmaxf(h0[1][s][r], 0.f);
                }
            }
        }
        // read broadcast av (wave-private LDS; program order guarantees vis.)
        float av[2][RR][9];
        #pragma unroll
        for (int n = 0; n < 2; ++n)
            #pragma unroll
            for (int r = 0; r < RR; ++r) {
                const float4 a03 = *reinterpret_cast<const float4*>(&A[wv][n][r][0]);
                const float4 a47 = *reinterpret_cast<const float4*>(&A[wv][n][r][4]);
                av[n][r][0] = a03.x; av[n][r][1] = a03.y;
                av[n][r][2] = a03.z; av[n][r][3] = a03.w;
                av[n][r][4] = a47.x; av[n][r][5] = a47.y;
                av[n][r][6] = a47.z; av[n][r][7] = a47.w;
                av[n][r][8] = A[wv][n][r][8];
            }

        // ====== h1 += av[k] * W1s[row k] — lazy LDS reads, uniform 9 =======
        #pragma unroll
        for (int k = 0; k < 9; ++k) {
            const float4 wm = *reinterpret_cast<const float4*>(wb + k * HH + c4);
            const float4 wl = *reinterpret_cast<const float4*>(wb + LW1L + k * HH + c4);
            #pragma unroll
            for (int r = 0; r < RR; ++r) {
                h1[0][0][r] = fmaf(av[0][r][k], wm.x, h1[0][0][r]);
                h1[0][1][r] = fmaf(av[0][r][k], wm.y, h1[0][1][r]);
                h1[0][2][r] = fmaf(av[0][r][k], wm.z, h1[0][2][r]);
                h1[0][3][r] = fmaf(av[0][r][k], wm.w, h1[0][3][r]);
                h1[1][0][r] = fmaf(av[1][r][k], wl.x, h1[1][0][r]);
                h1[1][1][r] = fmaf(av[1][r][k], wl.y, h1[1][1][r]);
                h1[1][2][r] = fmaf(av[1][r][k], wl.z, h1[1][2][r]);
                h1[1][3][r] = fmaf(av[1][r][k], wl.w, h1[1][3][r]);
            }
        }

        // finalize relu(h1) -> Bf (ONLY the nk members of group d)
        #pragma unroll
        for (int s = 0; s < 4; ++s) {
            const int k = c4 + s - off;
            if ((unsigned)k < (unsigned)nk) {
                #pragma unroll
                for (int r = 0; r < RR; ++r) {
                    Bf[wv][0][r][k] = fmaxf(h1[0][s][r], 0.f);
                    Bf[wv][1][r][k] = fmaxf(h1[1][s][r], 0.f);
                }
            }
        }
        // read r1 broadcast for this lane's net, fold into output accs
        float rb[RR][9];
        #pragma unroll
        for (int r = 0; r < RR; ++r) {
            const float4 b03 = *reinterpret_cast<const float4*>(&Bf[wv][nn][r][0]);
            const float4 b47 = *reinterpret_cast<const float4*>(&Bf[wv][nn][r][4]);
            rb[r][0] = b03.x; rb[r][1] = b03.y; rb[r][2] = b03.z; rb[r][3] = b03.w;
            rb[r][4] = b47.x; rb[r][5] = b47.y; rb[r][6] = b47.z; rb[r][7] = b47.w;
            rb[r][8] = Bf[wv][nn][r][8];
        }
        #pragma unroll
        for (int k = 0; k < 9; ++k) {
            const float w2k = wb[LW2 + k * 64 + lane];
            #pragma unroll
            for (int r = 0; r < RR; ++r)
                acc[r] = fmaf(rb[r][k], w2k, acc[r]);
        }

        // ================= outputs for dim d ===============================
        #pragma unroll
        for (int r = 0; r < RR; ++r) {
            const float mu  = __shfl(acc[r], d, 64);
            const float lv  = __shfl(acc[r], 32 + d, 64);
            const float ls2 = 0.5f * lv;
            lsum[r] += ls2;
            const float yd = (__shfl(xvr[r], d, 64) - mu) / (__expf(ls2) + EPSF);
            yprev[r] = yd;
            if (lane == d) ysave[r] = yd;
        }

        __syncthreads();   // WB[nxt] staged AND all waves done with WB[cur]
    }

    #pragma unroll
    for (int r = 0; r < RR; ++r) {
        if (lane < DD) out[(row0 + r) * DD + lane] = ysave[r];   // coalesced
        if (lane == 0) out[BB * DD + row0 + r] = lsum[r];
    }
}

// ---------------------------------------------------------------------------
// Fallback (no workspace): R1-style kernel.
// ---------------------------------------------------------------------------
__global__ __launch_bounds__(64, 1) void made_inv_fb(
    const float* __restrict__ x,
    const float* __restrict__ muW0, const float* __restrict__ mub0,
    const float* __restrict__ muW1, const float* __restrict__ mub1,
    const float* __restrict__ muW2, const float* __restrict__ mub2,
    const float* __restrict__ lvW0, const float* __restrict__ lvb0,
    const float* __restrict__ lvW1, const float* __restrict__ lvb1,
    const float* __restrict__ lvW2, const float* __restrict__ lvb2,
    float* __restrict__ out)
{
    const int lane    = threadIdx.x;
    const int rowBase = blockIdx.x * 4;
    const int hb      = lane << 2;
    int deg[4];
    #pragma unroll
    for (int s = 0; s < 4; ++s) deg[s] = ((hb + s) % 31) + 1;
    const float* Wp0[2] = {muW0, lvW0};
    const float* Bp0[2] = {mub0, lvb0};
    const float* Wp1[2] = {muW1, lvW1};
    const float* Bp1[2] = {mub1, lvb1};
    const float* Wp2[2] = {muW2, lvW2};
    float h0pre[2][4][4], h1pre[2][4][4], r1[2][4][4], yprev[4], lsum[4];
    #pragma unroll
    for (int n = 0; n < 2; ++n) {
        const float4 b0v = *reinterpret_cast<const float4*>(Bp0[n] + hb);
        const float4 b1v = *reinterpret_cast<const float4*>(Bp1[n] + hb);
        const float b0a[4] = {b0v.x, b0v.y, b0v.z, b0v.w};
        const float b1a[4] = {b1v.x, b1v.y, b1v.z, b1v.w};
        #pragma unroll
        for (int s = 0; s < 4; ++s)
            #pragma unroll
            for (int r = 0; r < 4; ++r) {
                h0pre[n][s][r] = b0a[s]; h1pre[n][s][r] = b1a[s]; r1[n][s][r] = 0.f;
            }
    }
    #pragma unroll
    for (int r = 0; r < 4; ++r) { yprev[r] = 0.f; lsum[r] = 0.f; }
    __shared__ float lds_a[2][4][12];
    for (int d = 0; d < DD; ++d) {
        if (d >= 1) {
            #pragma unroll
            for (int n = 0; n < 2; ++n) {
                const float4 w0 = *reinterpret_cast<const float4*>(Wp0[n] + (d - 1) * HH + hb);
                const float w0a[4] = {w0.x, w0.y, w0.z, w0.w};
                #pragma unroll
                for (int s = 0; s < 4; ++s)
                    #pragma unroll
                    for (int r = 0; r < 4; ++r)
                        h0pre[n][s][r] = fmaf(yprev[r], w0a[s], h0pre[n][s][r]);
            }
            #pragma unroll
            for (int n = 0; n < 2; ++n)
                #pragma unroll
                for (int s = 0; s < 4; ++s)
                    if (deg[s] == d) {
                        const int k = (hb + s - (d - 1)) / 31;
                        #pragma unroll
                        for (int r = 0; r < 4; ++r)
                            lds_a[n][r][k] = fmaxf(h0pre[n][s][r], 0.f);
                    }
            __syncthreads();
            const bool nine = (d <= 8);
            #pragma unroll
            for (int n = 0; n < 2; ++n) {
                const float* W1r = Wp1[n] + (size_t)(d - 1) * HH + hb;
                float4 w1v[9];
                #pragma unroll
                for (int k = 0; k < 8; ++k)
                    w1v[k] = *reinterpret_cast<const float4*>(W1r + k * 31 * HH);
                if (nine) w1v[8] = *reinterpret_cast<const float4*>(W1r + 8 * 31 * HH);
                #pragma unroll
                for (int r = 0; r < 4; ++r) {
                    const float4 a03 = *reinterpret_cast<const float4*>(&lds_a[n][r][0]);
                    const float4 a47 = *reinterpret_cast<const float4*>(&lds_a[n][r][4]);
                    const float av[8] = {a03.x, a03.y, a03.z, a03.w, a47.x, a47.y, a47.z, a47.w};
                    #pragma unroll
                    for (int k = 0; k < 8; ++k) {
                        const float wk[4] = {w1v[k].x, w1v[k].y, w1v[k].z, w1v[k].w};
                        #pragma unroll
                        for (int s = 0; s < 4; ++s)
                            h1pre[n][s][r] = fmaf(av[k], wk[s], h1pre[n][s][r]);
                    }
                    if (nine) {
                        const float a8 = lds_a[n][r][8];
                        const float wk[4] = {w1v[8].x, w1v[8].y, w1v[8].z, w1v[8].w};
                        #pragma unroll
                        for (int s = 0; s < 4; ++s)
                            h1pre[n][s][r] = fmaf(a8, wk[s], h1pre[n][s][r]);
                    }
                }
            }
            #pragma unroll
            for (int n = 0; n < 2; ++n)
                #pragma unroll
                for (int s = 0; s < 4; ++s)
                    if (deg[s] == d)
                        #pragma unroll
                        for (int r = 0; r < 4; ++r)
                            r1[n][s][r] = fmaxf(h1pre[n][s][r], 0.f);
            __syncthreads();
        }
        float w2v[2][4];
        #pragma unroll
        for (int n = 0; n < 2; ++n)
            #pragma unroll
            for (int s = 0; s < 4; ++s)
                w2v[n][s] = Wp2[n][(hb + s) * DD + d];
        float red[2][4];
        #pragma unroll
        for (int n = 0; n < 2; ++n)
            #pragma unroll
            for (int r = 0; r < 4; ++r) {
                float p = 0.f;
                #pragma unroll
                for (int s = 0; s < 4; ++s) p = fmaf(r1[n][s][r], w2v[n][s], p);
                red[n][r] = p;
            }
        #pragma unroll
        for (int m = 1; m < 64; m <<= 1)
            #pragma unroll
            for (int n = 0; n < 2; ++n)
                #pragma unroll
                for (int r = 0; r < 4; ++r)
                    red[n][r] += __shfl_xor(red[n][r], m, 64);
        const float b2m = mub2[d], b2l = lvb2[d];
        #pragma unroll
        for (int r = 0; r < 4; ++r) {
            const float mu = red[0][r] + b2m;
            const float logstd = 0.5f * (red[1][r] + b2l);
            lsum[r] += logstd;
            const float yd = (x[(rowBase + r) * DD + d] - mu) / (__expf(logstd) + EPSF);
            yprev[r] = yd;
            if (lane == 0) out[(rowBase + r) * DD + d] = yd;
        }
    }
    if (lane == 0)
        #pragma unroll
        for (int r = 0; r < 4; ++r) out[BB * DD + rowBase + r] = lsum[r];
}

extern "C" void kernel_launch(void* const* d_in, const int* in_sizes, int n_in,
                              void* d_out, int out_size, void* d_ws, size_t ws_size,
                              hipStream_t stream) {
    const float* x    = (const float*)d_in[0];
    const float* muW0 = (const float*)d_in[1];
    const float* mub0 = (const float*)d_in[2];
    const float* muW1 = (const float*)d_in[3];
    const float* mub1 = (const float*)d_in[4];
    const float* muW2 = (const float*)d_in[5];
    const float* mub2 = (const float*)d_in[6];
    const float* lvW0 = (const float*)d_in[7];
    const float* lvb0 = (const float*)d_in[8];
    const float* lvW1 = (const float*)d_in[9];
    const float* lvb1 = (const float*)d_in[10];
    const float* lvW2 = (const float*)d_in[11];
    const float* lvb2 = (const float*)d_in[12];
    float* out = (float*)d_out;

    if (ws_size >= WSNEED) {
        float* ws = (float*)d_ws;
        made_prep<<<dim3(832), dim3(64), 0, stream>>>(
            muW0, mub0, muW1, mub1, muW2,
            lvW0, lvb0, lvW1, lvb1, lvW2, ws);
        made_main<<<dim3(BB / (4 * RR)), dim3(256), 0, stream>>>(ws, x, mub2, lvb2, out);
    } else {
        made_inv_fb<<<dim3(BB / 4), dim3(64), 0, stream>>>(x,
            muW0, mub0, muW1, mub1, muW2, mub2,
            lvW0, lvb0, lvW1, lvb1, lvW2, lvb2, out);
    }
}